// Round 3
// baseline (533.294 us; speedup 1.0000x reference)
//
#include <hip/hip_runtime.h>
#include <math.h>
#include <stdint.h>

#define T_DIM 2048
#define B_DIM 16
#define D_DIM 1024
#define N_DIM 64
#define EPSV 1e-6f

#define NT 256   // proj row: 0-63 k, 64-127 v, 128-191 q, 192-255 sigmoid(beta)

#define TWO_LOG2E 2.885390081777927f
#define LOG2E     1.4426950408889634f

typedef _Float16 half8 __attribute__((ext_vector_type(8)));
typedef float    f32x16_t __attribute__((ext_vector_type(16)));
union F4H8 { float4 f; half8 h; };

// ---- fast math ----
__device__ __forceinline__ float fast_rcp(float x) {
    return __builtin_amdgcn_rcpf(x);
}
__device__ __forceinline__ float sigmoid_fast(float x) {
    return fast_rcp(1.f + __builtin_amdgcn_exp2f(-LOG2E * x));
}
__device__ __forceinline__ float tanh_from_scaled(float xs) {
    float e = __builtin_amdgcn_exp2f(xs);
    return 1.f - 2.f * fast_rcp(e + 1.f);
}

// DPP all-reduce within each 16-lane row.
template<int CTRL>
__device__ __forceinline__ float dpp_radd(float x) {
    int y = __builtin_amdgcn_update_dpp(0, __float_as_int(x), CTRL, 0xf, 0xf, true);
    return x + __int_as_float(y);
}
__device__ __forceinline__ float reduce16(float x) {
    x = dpp_radd<0xB1>(x);
    x = dpp_radd<0x4E>(x);
    x = dpp_radd<0x124>(x);
    x = dpp_radd<0x128>(x);
    return x;
}

// async global -> LDS DMA, 16 B per lane; LDS base wave-uniform, lane i -> base + 16*i
__device__ __forceinline__ void dma16(const float* g, float* l) {
    __builtin_amdgcn_global_load_lds((const __attribute__((address_space(1))) void*)g,
                                     (__attribute__((address_space(3))) void*)l, 16, 0, 0);
}

// ======================= W prepass (unchanged) =======================
__global__ __launch_bounds__(256) void wprep_kernel(
    const float* __restrict__ Wk, const float* __restrict__ Wv,
    const float* __restrict__ Wq, const float* __restrict__ Wb,
    float4* __restrict__ w2)
{
    const int c  = threadIdx.x;           // 0..255
    const int k8 = blockIdx.x;            // 0..127
    const float* Wsrc = (c < 64) ? Wk : (c < 128) ? Wv : (c < 192) ? Wq : Wb;
    const float4* src = (const float4*)(Wsrc + (size_t)(c & 63) * D_DIM + k8 * 8);
    const float4 f0 = src[0], f1 = src[1];
    float f[8] = {f0.x, f0.y, f0.z, f0.w, f1.x, f1.y, f1.z, f1.w};
    F4H8 hi, lo;
    #pragma unroll
    for (int j = 0; j < 8; ++j) {
        _Float16 h = (_Float16)f[j];
        hi.h[j] = h;
        lo.h[j] = (_Float16)(f[j] - (float)h);
    }
    w2[(size_t)(2 * k8)     * 256 + c] = hi.f;
    w2[(size_t)(2 * k8 + 1) * 256 + c] = lo.f;
}

// ======================= MFMA projection GEMM (unchanged) =======================
#define BM 64

__global__ __launch_bounds__(256) void proj_gemm_mfma(
    const float* __restrict__ x,
    const float4* __restrict__ w2,
    const float* __restrict__ bb,
    float* __restrict__ proj)
{
    __shared__ float  As32[2][BM * 32];   // fp32 staging, 8 KB each
    __shared__ float4 Ahl[2][BM * 8];     // f16 hi/lo slots, 8 KB each

    const int tid  = threadIdx.x;
    const int w    = tid >> 6;            // wave = col-group wn 0..3
    const int lane = tid & 63;
    const int m0   = blockIdx.x * BM;
    const int cl   = lane & 31;
    const int kh   = lane >> 5;           // k-half of the MFMA operand

    f32x16_t acc[2][2] = {};              // [tm][tn], wave tile 64M x 64N

    auto stage = [&](int buf, int t) {    // fp32 x tile for K-step t
        #pragma unroll
        for (int i = 0; i < 2; ++i) {
            const int rb    = w * 16 + i * 8;
            const int row   = rb + (lane >> 3);
            const int sslot = (lane & 7) ^ ((lane >> 3) & 7);   // pre-swizzled source
            dma16(x + (size_t)(m0 + row) * D_DIM + 32 * t + 4 * sslot,
                  &As32[buf][rb * 32]);
        }
    };
    auto convert = [&](int bs, int bd) {  // fp32 -> f16 hi/lo, once per element
        const int row = tid >> 2, c = tid & 3, sw = row & 7;
        const float4* s32 = (const float4*)&As32[bs][0];
        const float4 fA = s32[row * 8 + ((2 * c)     ^ sw)];
        const float4 fB = s32[row * 8 + ((2 * c + 1) ^ sw)];
        float f[8] = {fA.x, fA.y, fA.z, fA.w, fB.x, fB.y, fB.z, fB.w};
        F4H8 hi, lo;
        #pragma unroll
        for (int j = 0; j < 8; ++j) {
            _Float16 h = (_Float16)f[j];
            hi.h[j] = h;
            lo.h[j] = (_Float16)(f[j] - (float)h);
        }
        Ahl[bd][row * 8 + ((2 * c)     ^ sw)] = hi.f;
        Ahl[bd][row * 8 + ((2 * c + 1) ^ sw)] = lo.f;
    };

    stage(0, 0);
    stage(1, 1);
    __syncthreads();          // both fp32 tiles landed
    convert(0, 0);            // Ahl[0] <- step 0
    __syncthreads();

    for (int t = 0; t < 32; ++t) {
        if (t + 2 < 32) stage(t & 1, t + 2);        // As32[t&1] consumed last iter

        // B fragments for step t straight from L2 (frag-ordered w2)
        half8 bh[2][2], bl[2][2];                   // [ksub][tn]
        #pragma unroll
        for (int ks = 0; ks < 2; ++ks) {
            const int ksg = 2 * t + ks;
            #pragma unroll
            for (int tn = 0; tn < 2; ++tn) {
                const int col = w * 64 + tn * 32 + cl;
                F4H8 th, tl;
                th.f = w2[(size_t)(4 * ksg + 2 * kh)     * 256 + col];
                tl.f = w2[(size_t)(4 * ksg + 2 * kh + 1) * 256 + col];
                bh[ks][tn] = th.h; bl[ks][tn] = tl.h;
            }
        }

        if (t + 1 < 32) convert((t + 1) & 1, (t + 1) & 1);   // hides B-load latency

        const float4* At = &Ahl[t & 1][0];
        #pragma unroll
        for (int ks = 0; ks < 2; ++ks) {
            half8 ah[2], al[2];
            #pragma unroll
            for (int tm = 0; tm < 2; ++tm) {
                const int row = tm * 32 + cl;
                const int sw  = row & 7;
                F4H8 th, tl;
                th.f = At[row * 8 + ((4 * ks + 2 * kh)     ^ sw)];
                tl.f = At[row * 8 + ((4 * ks + 2 * kh + 1) ^ sw)];
                ah[tm] = th.h; al[tm] = tl.h;
            }
            #pragma unroll
            for (int tm = 0; tm < 2; ++tm)
                #pragma unroll
                for (int tn = 0; tn < 2; ++tn) {
                    acc[tm][tn] = __builtin_amdgcn_mfma_f32_32x32x16_f16(ah[tm], bh[ks][tn], acc[tm][tn], 0, 0, 0);
                    acc[tm][tn] = __builtin_amdgcn_mfma_f32_32x32x16_f16(ah[tm], bl[ks][tn], acc[tm][tn], 0, 0, 0);
                    acc[tm][tn] = __builtin_amdgcn_mfma_f32_32x32x16_f16(al[tm], bh[ks][tn], acc[tm][tn], 0, 0, 0);
                }
        }
        __syncthreads();     // drains DMA(t+2); releases As32/Ahl buffers
    }

    // Epilogue: C/D layout col = lane&31, row = (r&3) + 8*(r>>2) + 4*(lane>>5)
    #pragma unroll
    for (int tn = 0; tn < 2; ++tn) {
        const int  gcol   = w * 64 + tn * 32 + cl;
        const bool isbeta = (gcol >= 192);
        const float bias  = isbeta ? bb[gcol - 192] : 0.f;
        #pragma unroll
        for (int tm = 0; tm < 2; ++tm) {
            #pragma unroll
            for (int r = 0; r < 16; ++r) {
                const int rowin = (r & 3) + 8 * (r >> 2) + 4 * kh;
                const size_t grow = (size_t)(m0 + tm * 32 + rowin);
                float v = acc[tm][tn][r];
                if (isbeta) v = sigmoid_fast(v + bias);
                proj[grow * NT + gcol] = v;
            }
        }
    }
}

// ======================= k-normalization (unchanged) =======================
__global__ __launch_bounds__(256) void knorm_kernel(float* __restrict__ proj)
{
    const int w = (int)((blockIdx.x * blockDim.x + threadIdx.x) >> 6);
    const int lane = threadIdx.x & 63;
    float k = proj[(size_t)w * NT + lane];
    float s = k * k;
    #pragma unroll
    for (int off = 32; off; off >>= 1) s += __shfl_xor(s, off, 64);
    proj[(size_t)w * NT + lane] = k * fast_rcp(sqrtf(s) + EPSV);
}

// ======================= recurrence: rotated dual-reduce pipeline =======================
// Step t's y1-reduce is deferred and interleaved with step t+1's y2-reduce:
// the two 4-stage DPP chains fill each other's DPP wait-state hazards.
// Post-reduce critical path shortened to ONE fma via off-chain precompute:
//   arg = (vC - 2L*y2)*kn + beC*s  =  fma(-Q, y2, P),  P = fma(vC,kn,beC*s), Q = 2L*kn.
__device__ __forceinline__ void step_rot(float4& s, const float4 kn, const float4 q,
                                         const float vC, const float beC,
                                         const int cap, const int l,
                                         float& ysel, float& p1)
{
    float p2 = (s.x * kn.x + s.y * kn.y) + (s.z * kn.z + s.w * kn.w);
    // off-chain precompute: overlaps the reduce stalls
    const float Px = fmaf(vC, kn.x, beC * s.x);
    const float Py = fmaf(vC, kn.y, beC * s.y);
    const float Pz = fmaf(vC, kn.z, beC * s.z);
    const float Pw = fmaf(vC, kn.w, beC * s.w);
    const float Qx = TWO_LOG2E * kn.x, Qy = TWO_LOG2E * kn.y;
    const float Qz = TWO_LOG2E * kn.z, Qw = TWO_LOG2E * kn.w;
    // interleaved dual all-reduce: p2 = y2(step t) [critical], p1 = y1(step t-1)
    p2 = dpp_radd<0xB1>(p2);   p1 = dpp_radd<0xB1>(p1);
    p2 = dpp_radd<0x4E>(p2);   p1 = dpp_radd<0x4E>(p1);
    p2 = dpp_radd<0x124>(p2);  p1 = dpp_radd<0x124>(p1);
    p2 = dpp_radd<0x128>(p2);  p1 = dpp_radd<0x128>(p1);
    ysel = (l == cap) ? p1 : ysel;          // capture step t-1's output
    s.x = tanh_from_scaled(fmaf(-Qx, p2, Px));
    s.y = tanh_from_scaled(fmaf(-Qy, p2, Py));
    s.z = tanh_from_scaled(fmaf(-Qz, p2, Pz));
    s.w = tanh_from_scaled(fmaf(-Qw, p2, Pw));
    p1 = (s.x * q.x + s.y * q.y) + (s.z * q.z + s.w * q.w);   // y1 partial, reduced next step
}

__device__ __forceinline__ void phase16(const float (*buf)[256], int t0,
                                        float4& s, int l, int i, int b,
                                        float* __restrict__ out)
{
    const float* s0 = &buf[0][0];
    const float* s1 = &buf[1][0];
    float4 kn0 = *(const float4*)(s0 + 4 * l);
    float4 q0  = *(const float4*)(s0 + 128 + 4 * l);
    float  vC0 = s0[64 + i] * TWO_LOG2E;
    float  beC0= s0[192 + i] * TWO_LOG2E;
    float4 kn1 = *(const float4*)(s1 + 4 * l);
    float4 q1  = *(const float4*)(s1 + 128 + 4 * l);
    float  vC1 = s1[64 + i] * TWO_LOG2E;
    float  beC1= s1[192 + i] * TWO_LOG2E;

    float ysel = 0.f, p1 = 0.f;
    for (int j = 0; j < 8; ++j) {
        const int sp = 2 * j;
        // prefetch next iteration's rows (clamped; row-15 re-read is harmless)
        const int pA = (sp + 2 < 16) ? sp + 2 : 15;
        const int pB = (sp + 3 < 16) ? sp + 3 : 15;
        const float* sA = &buf[pA][0];
        const float* sB = &buf[pB][0];
        float4 knA = *(const float4*)(sA + 4 * l);
        float4 qA  = *(const float4*)(sA + 128 + 4 * l);
        float  vCA = sA[64 + i] * TWO_LOG2E;
        float  beCA= sA[192 + i] * TWO_LOG2E;
        float4 knB = *(const float4*)(sB + 4 * l);
        float4 qB  = *(const float4*)(sB + 128 + 4 * l);
        float  vCB = sB[64 + i] * TWO_LOG2E;
        float  beCB= sB[192 + i] * TWO_LOG2E;

        step_rot(s, kn0, q0, vC0, beC0, sp - 1, l, ysel, p1);
        step_rot(s, kn1, q1, vC1, beC1, sp,     l, ysel, p1);

        kn0 = knA; q0 = qA; vC0 = vCA; beC0 = beCA;
        kn1 = knB; q1 = qB; vC1 = vCB; beC1 = beCB;
    }
    // finish step 15's y1
    p1 = reduce16(p1);
    ysel = (l == 15) ? p1 : ysel;
    const float w = ysel;
    out[(size_t)(t0 + l) * (B_DIM * N_DIM) + b * 64 + i] = w * w * sigmoid_fast(w);
}

__global__ __launch_bounds__(128, 1) void recur6_kernel(
    const float* __restrict__ proj,
    const float* __restrict__ S0,
    float* __restrict__ out)   // [T,B,N] then S_final [B,N,N]
{
    __shared__ float bufA[16][256];
    __shared__ float bufB[16][256];

    const int wid  = blockIdx.x;          // [0,256)
    const int wv   = threadIdx.x >> 6;    // 0 = consumer, 1 = producer
    const int lane = threadIdx.x & 63;
    const int l = lane & 15;
    const int r = lane >> 4;
    const int b = wid >> 4;
    const int i = ((wid & 15) << 2) + r;

    if (wv == 1) {
        #pragma unroll
        for (int j = 0; j < 16; ++j)
            dma16(proj + ((size_t)j * B_DIM + b) * NT + 4 * lane, &bufA[j][0]);
        __syncthreads();
        for (int t0 = 0; t0 < T_DIM; t0 += 32) {
            #pragma unroll
            for (int j = 0; j < 16; ++j) {
                int row = t0 + 16 + j; if (row > T_DIM - 1) row = T_DIM - 1;
                dma16(proj + ((size_t)row * B_DIM + b) * NT + 4 * lane, &bufB[j][0]);
            }
            __syncthreads();
            #pragma unroll
            for (int j = 0; j < 16; ++j) {
                int row = t0 + 32 + j; if (row > T_DIM - 1) row = T_DIM - 1;
                dma16(proj + ((size_t)row * B_DIM + b) * NT + 4 * lane, &bufA[j][0]);
            }
            __syncthreads();
        }
    } else {
        __builtin_amdgcn_s_setprio(1);        // consumer is the critical wave
        float4 s = *(const float4*)(S0 + ((size_t)(b * 64 + i) << 6) + 4 * l);
        __syncthreads();
        for (int t0 = 0; t0 < T_DIM; t0 += 32) {
            phase16(bufA, t0, s, l, i, b, out);
            __syncthreads();
            phase16(bufB, t0 + 16, s, l, i, b, out);
            __syncthreads();
        }
        *(float4*)(out + (size_t)T_DIM * B_DIM * N_DIM +
                   ((size_t)(b * 64 + i) << 6) + 4 * l) = s;
    }
}

extern "C" void kernel_launch(void* const* d_in, const int* in_sizes, int n_in,
                              void* d_out, int out_size, void* d_ws, size_t ws_size,
                              hipStream_t stream) {
    const float* x  = (const float*)d_in[0];
    const float* S0 = (const float*)d_in[1];
    const float* Wk = (const float*)d_in[2];
    const float* Wv = (const float*)d_in[3];
    const float* Wq = (const float*)d_in[4];
    const float* Wb = (const float*)d_in[5];
    const float* bb = (const float*)d_in[6];
    float* out  = (float*)d_out;
    float* proj = (float*)d_ws;                       // 32768*256 f32 = 32 MB
    float4* w2  = (float4*)((char*)d_ws + (size_t)32768 * 256 * 4);   // +1 MB

    wprep_kernel<<<dim3(128), dim3(256), 0, stream>>>(Wk, Wv, Wq, Wb, w2);
    proj_gemm_mfma<<<dim3(32768 / BM), dim3(256), 0, stream>>>(x, w2, bb, proj);
    knorm_kernel<<<dim3((32768 * 64) / 256), dim3(256), 0, stream>>>(proj);
    recur6_kernel<<<dim3(256), dim3(128), 0, stream>>>(proj, S0, out);
}

// Round 4
// 501.243 us; speedup vs baseline: 1.0639x; 1.0639x over previous
//
#include <hip/hip_runtime.h>
#include <math.h>
#include <stdint.h>

#define T_DIM 2048
#define B_DIM 16
#define D_DIM 1024
#define N_DIM 64
#define EPSV 1e-6f

#define NT 256   // proj row: 0-63 k, 64-127 v, 128-191 q, 192-255 sigmoid(beta)

#define TWO_LOG2E 2.885390081777927f
#define LOG2E     1.4426950408889634f

typedef _Float16 half8 __attribute__((ext_vector_type(8)));
typedef float    f32x16_t __attribute__((ext_vector_type(16)));
union F4H8 { float4 f; half8 h; };

// ---- fast math ----
__device__ __forceinline__ float fast_rcp(float x) {
    return __builtin_amdgcn_rcpf(x);
}
__device__ __forceinline__ float sigmoid_fast(float x) {
    return fast_rcp(1.f + __builtin_amdgcn_exp2f(-LOG2E * x));
}

// DPP add: x += dpp_perm(x)
template<int CTRL>
__device__ __forceinline__ float dpp_radd(float x) {
    int y = __builtin_amdgcn_update_dpp(0, __float_as_int(x), CTRL, 0xf, 0xf, true);
    return x + __int_as_float(y);
}

// Full wave64 reduce -> wave-uniform scalar (SGPR broadcast).
// 4-stage butterfly within 16-lane rows (all lanes hold row sum), then
// row_bcast15 (rows 1,3 += rows 0,2) + row_bcast31 (rows 2,3 += rows 0-1)
// puts the full sum in lanes 48-63; readlane 63 broadcasts it.
__device__ __forceinline__ float reduce64_rl(float x) {
    x = dpp_radd<0xB1>(x);    // quad_perm [1,0,3,2]
    x = dpp_radd<0x4E>(x);    // quad_perm [2,3,0,1]
    x = dpp_radd<0x124>(x);   // row_ror:4
    x = dpp_radd<0x128>(x);   // row_ror:8
    x = dpp_radd<0x142>(x);   // row_bcast15
    x = dpp_radd<0x143>(x);   // row_bcast31
    return __int_as_float(__builtin_amdgcn_readlane(__float_as_int(x), 63));
}

// async global -> LDS DMA, 16 B per lane; LDS base wave-uniform, lane i -> base + 16*i
__device__ __forceinline__ void dma16(const float* g, float* l) {
    __builtin_amdgcn_global_load_lds((const __attribute__((address_space(1))) void*)g,
                                     (__attribute__((address_space(3))) void*)l, 16, 0, 0);
}

// ======================= W prepass (unchanged) =======================
__global__ __launch_bounds__(256) void wprep_kernel(
    const float* __restrict__ Wk, const float* __restrict__ Wv,
    const float* __restrict__ Wq, const float* __restrict__ Wb,
    float4* __restrict__ w2)
{
    const int c  = threadIdx.x;           // 0..255
    const int k8 = blockIdx.x;            // 0..127
    const float* Wsrc = (c < 64) ? Wk : (c < 128) ? Wv : (c < 192) ? Wq : Wb;
    const float4* src = (const float4*)(Wsrc + (size_t)(c & 63) * D_DIM + k8 * 8);
    const float4 f0 = src[0], f1 = src[1];
    float f[8] = {f0.x, f0.y, f0.z, f0.w, f1.x, f1.y, f1.z, f1.w};
    F4H8 hi, lo;
    #pragma unroll
    for (int j = 0; j < 8; ++j) {
        _Float16 h = (_Float16)f[j];
        hi.h[j] = h;
        lo.h[j] = (_Float16)(f[j] - (float)h);
    }
    w2[(size_t)(2 * k8)     * 256 + c] = hi.f;
    w2[(size_t)(2 * k8 + 1) * 256 + c] = lo.f;
}

// ======================= MFMA projection GEMM (unchanged) =======================
#define BM 64

__global__ __launch_bounds__(256) void proj_gemm_mfma(
    const float* __restrict__ x,
    const float4* __restrict__ w2,
    const float* __restrict__ bb,
    float* __restrict__ proj)
{
    __shared__ float  As32[2][BM * 32];   // fp32 staging, 8 KB each
    __shared__ float4 Ahl[2][BM * 8];     // f16 hi/lo slots, 8 KB each

    const int tid  = threadIdx.x;
    const int w    = tid >> 6;            // wave = col-group wn 0..3
    const int lane = tid & 63;
    const int m0   = blockIdx.x * BM;
    const int cl   = lane & 31;
    const int kh   = lane >> 5;           // k-half of the MFMA operand

    f32x16_t acc[2][2] = {};              // [tm][tn], wave tile 64M x 64N

    auto stage = [&](int buf, int t) {    // fp32 x tile for K-step t
        #pragma unroll
        for (int i = 0; i < 2; ++i) {
            const int rb    = w * 16 + i * 8;
            const int row   = rb + (lane >> 3);
            const int sslot = (lane & 7) ^ ((lane >> 3) & 7);   // pre-swizzled source
            dma16(x + (size_t)(m0 + row) * D_DIM + 32 * t + 4 * sslot,
                  &As32[buf][rb * 32]);
        }
    };
    auto convert = [&](int bs, int bd) {  // fp32 -> f16 hi/lo, once per element
        const int row = tid >> 2, c = tid & 3, sw = row & 7;
        const float4* s32 = (const float4*)&As32[bs][0];
        const float4 fA = s32[row * 8 + ((2 * c)     ^ sw)];
        const float4 fB = s32[row * 8 + ((2 * c + 1) ^ sw)];
        float f[8] = {fA.x, fA.y, fA.z, fA.w, fB.x, fB.y, fB.z, fB.w};
        F4H8 hi, lo;
        #pragma unroll
        for (int j = 0; j < 8; ++j) {
            _Float16 h = (_Float16)f[j];
            hi.h[j] = h;
            lo.h[j] = (_Float16)(f[j] - (float)h);
        }
        Ahl[bd][row * 8 + ((2 * c)     ^ sw)] = hi.f;
        Ahl[bd][row * 8 + ((2 * c + 1) ^ sw)] = lo.f;
    };

    stage(0, 0);
    stage(1, 1);
    __syncthreads();          // both fp32 tiles landed
    convert(0, 0);            // Ahl[0] <- step 0
    __syncthreads();

    for (int t = 0; t < 32; ++t) {
        if (t + 2 < 32) stage(t & 1, t + 2);        // As32[t&1] consumed last iter

        // B fragments for step t straight from L2 (frag-ordered w2)
        half8 bh[2][2], bl[2][2];                   // [ksub][tn]
        #pragma unroll
        for (int ks = 0; ks < 2; ++ks) {
            const int ksg = 2 * t + ks;
            #pragma unroll
            for (int tn = 0; tn < 2; ++tn) {
                const int col = w * 64 + tn * 32 + cl;
                F4H8 th, tl;
                th.f = w2[(size_t)(4 * ksg + 2 * kh)     * 256 + col];
                tl.f = w2[(size_t)(4 * ksg + 2 * kh + 1) * 256 + col];
                bh[ks][tn] = th.h; bl[ks][tn] = tl.h;
            }
        }

        if (t + 1 < 32) convert((t + 1) & 1, (t + 1) & 1);   // hides B-load latency

        const float4* At = &Ahl[t & 1][0];
        #pragma unroll
        for (int ks = 0; ks < 2; ++ks) {
            half8 ah[2], al[2];
            #pragma unroll
            for (int tm = 0; tm < 2; ++tm) {
                const int row = tm * 32 + cl;
                const int sw  = row & 7;
                F4H8 th, tl;
                th.f = At[row * 8 + ((4 * ks + 2 * kh)     ^ sw)];
                tl.f = At[row * 8 + ((4 * ks + 2 * kh + 1) ^ sw)];
                ah[tm] = th.h; al[tm] = tl.h;
            }
            #pragma unroll
            for (int tm = 0; tm < 2; ++tm)
                #pragma unroll
                for (int tn = 0; tn < 2; ++tn) {
                    acc[tm][tn] = __builtin_amdgcn_mfma_f32_32x32x16_f16(ah[tm], bh[ks][tn], acc[tm][tn], 0, 0, 0);
                    acc[tm][tn] = __builtin_amdgcn_mfma_f32_32x32x16_f16(ah[tm], bl[ks][tn], acc[tm][tn], 0, 0, 0);
                    acc[tm][tn] = __builtin_amdgcn_mfma_f32_32x32x16_f16(al[tm], bh[ks][tn], acc[tm][tn], 0, 0, 0);
                }
        }
        __syncthreads();     // drains DMA(t+2); releases As32/Ahl buffers
    }

    // Epilogue: C/D layout col = lane&31, row = (r&3) + 8*(r>>2) + 4*(lane>>5)
    #pragma unroll
    for (int tn = 0; tn < 2; ++tn) {
        const int  gcol   = w * 64 + tn * 32 + cl;
        const bool isbeta = (gcol >= 192);
        const float bias  = isbeta ? bb[gcol - 192] : 0.f;
        #pragma unroll
        for (int tm = 0; tm < 2; ++tm) {
            #pragma unroll
            for (int r = 0; r < 16; ++r) {
                const int rowin = (r & 3) + 8 * (r >> 2) + 4 * kh;
                const size_t grow = (size_t)(m0 + tm * 32 + rowin);
                float v = acc[tm][tn][r];
                if (isbeta) v = sigmoid_fast(v + bias);
                proj[grow * NT + gcol] = v;
            }
        }
    }
}

// ======================= k-normalization (unchanged) =======================
__global__ __launch_bounds__(256) void knorm_kernel(float* __restrict__ proj)
{
    const int w = (int)((blockIdx.x * blockDim.x + threadIdx.x) >> 6);
    const int lane = threadIdx.x & 63;
    float k = proj[(size_t)w * NT + lane];
    float s = k * k;
    #pragma unroll
    for (int off = 32; off; off >>= 1) s += __shfl_xor(s, off, 64);
    proj[(size_t)w * NT + lane] = k * fast_rcp(sqrtf(s) + EPSV);
}

// ======================= recurrence: 1 col/lane, 1 row/wave =======================
// Each consumer wave owns one (b,i) row of S: lane = column. Per step:
//   y2 = reduce64(s*kn); arg = fma(-2L*kn, y2, fma(vC,kn,beC*s));
//   s = 1 - 2/(2^arg+1);  y1 = reduce64(s*q); capture at lane==t&63.
// Only 2 transcendentals/step (vs 8 at 4 cols/lane). Straight-line code —
// compiler interleaves the two independent reduce chains (round-3 lesson:
// manual interleave regresses).
__device__ __forceinline__ void step_r7(float& s, const float kn, const float q,
                                        const float Q2, const float vC, const float beC,
                                        const int cap, const int lane, float& ysel)
{
    float y2 = reduce64_rl(s * kn);
    float P  = fmaf(vC, kn, beC * s);
    float e  = __builtin_amdgcn_exp2f(fmaf(-Q2, y2, P));
    s = fmaf(-2.f, fast_rcp(e + 1.f), 1.f);
    float y1 = reduce64_rl(s * q);
    ysel = (lane == cap) ? y1 : ysel;
}

__device__ __forceinline__ void phase16_r7(const float (*buf)[256], int t0,
                                           float& s, int lane, int i, float& ysel)
{
    const float* r0 = &buf[0][0];
    const float* r1 = &buf[1][0];
    float kn0 = r0[lane], q0 = r0[128 + lane];
    float vC0 = r0[64 + i] * TWO_LOG2E, beC0 = r0[192 + i] * TWO_LOG2E;
    float kn1 = r1[lane], q1 = r1[128 + lane];
    float vC1 = r1[64 + i] * TWO_LOG2E, beC1 = r1[192 + i] * TWO_LOG2E;

    for (int j = 0; j < 8; ++j) {
        const int sp = 2 * j;
        // prefetch next iteration's rows (clamped; row-15 re-read is harmless)
        const int pA = (sp + 2 < 16) ? sp + 2 : 15;
        const int pB = (sp + 3 < 16) ? sp + 3 : 15;
        const float* rA = &buf[pA][0];
        const float* rB = &buf[pB][0];
        float knA = rA[lane], qA = rA[128 + lane];
        float vCA = rA[64 + i] * TWO_LOG2E, beCA = rA[192 + i] * TWO_LOG2E;
        float knB = rB[lane], qB = rB[128 + lane];
        float vCB = rB[64 + i] * TWO_LOG2E, beCB = rB[192 + i] * TWO_LOG2E;

        step_r7(s, kn0, q0, TWO_LOG2E * kn0, vC0, beC0, (t0 + sp) & 63,     lane, ysel);
        step_r7(s, kn1, q1, TWO_LOG2E * kn1, vC1, beC1, (t0 + sp + 1) & 63, lane, ysel);

        kn0 = knA; q0 = qA; vC0 = vCA; beC0 = beCA;
        kn1 = knB; q1 = qB; vC1 = vCB; beC1 = beCB;
    }
}

__global__ __launch_bounds__(320, 1) void recur7_kernel(
    const float* __restrict__ proj,
    const float* __restrict__ S0,
    float* __restrict__ out)   // [T,B,N] then S_final [B,N,N]
{
    __shared__ float bufA[16][256];
    __shared__ float bufB[16][256];

    const int wid  = blockIdx.x;          // [0,256)
    const int wv   = threadIdx.x >> 6;    // 0-3 consumers, 4 producer
    const int lane = threadIdx.x & 63;
    const int b = wid >> 4;
    const int i = ((wid & 15) << 2) + wv; // consumer's row (wv < 4)

    if (wv == 4) {
        // ---- producer: identical staging skeleton to the proven kernel ----
        #pragma unroll
        for (int j = 0; j < 16; ++j)
            dma16(proj + ((size_t)j * B_DIM + b) * NT + 4 * lane, &bufA[j][0]);
        __syncthreads();
        for (int t0 = 0; t0 < T_DIM; t0 += 32) {
            #pragma unroll
            for (int j = 0; j < 16; ++j) {
                int row = t0 + 16 + j; if (row > T_DIM - 1) row = T_DIM - 1;
                dma16(proj + ((size_t)row * B_DIM + b) * NT + 4 * lane, &bufB[j][0]);
            }
            __syncthreads();
            #pragma unroll
            for (int j = 0; j < 16; ++j) {
                int row = t0 + 32 + j; if (row > T_DIM - 1) row = T_DIM - 1;
                dma16(proj + ((size_t)row * B_DIM + b) * NT + 4 * lane, &bufA[j][0]);
            }
            __syncthreads();
        }
    } else {
        // ---- consumer: one row of S, lane = column ----
        float s = S0[((size_t)(b * 64 + i) << 6) + lane];
        float ysel = 0.f;
        __syncthreads();                      // prologue: bufA ready
        for (int t0 = 0; t0 < T_DIM; t0 += 32) {
            phase16_r7(bufA, t0, s, lane, i, ysel);
            __syncthreads();
            phase16_r7(bufB, t0 + 16, s, lane, i, ysel);
            if ((t0 & 63) == 32) {            // 64-step group complete
                const float w = ysel;
                out[(size_t)(t0 - 32 + lane) * (B_DIM * N_DIM) + b * 64 + i] =
                    w * w * sigmoid_fast(w);
            }
            __syncthreads();
        }
        // S_final: coalesced row store
        out[(size_t)T_DIM * B_DIM * N_DIM + ((size_t)(b * 64 + i) << 6) + lane] = s;
    }
}

extern "C" void kernel_launch(void* const* d_in, const int* in_sizes, int n_in,
                              void* d_out, int out_size, void* d_ws, size_t ws_size,
                              hipStream_t stream) {
    const float* x  = (const float*)d_in[0];
    const float* S0 = (const float*)d_in[1];
    const float* Wk = (const float*)d_in[2];
    const float* Wv = (const float*)d_in[3];
    const float* Wq = (const float*)d_in[4];
    const float* Wb = (const float*)d_in[5];
    const float* bb = (const float*)d_in[6];
    float* out  = (float*)d_out;
    float* proj = (float*)d_ws;                       // 32768*256 f32 = 32 MB
    float4* w2  = (float4*)((char*)d_ws + (size_t)32768 * 256 * 4);   // +1 MB

    wprep_kernel<<<dim3(128), dim3(256), 0, stream>>>(Wk, Wv, Wq, Wb, w2);
    proj_gemm_mfma<<<dim3(32768 / BM), dim3(256), 0, stream>>>(x, w2, bb, proj);
    knorm_kernel<<<dim3((32768 * 64) / 256), dim3(256), 0, stream>>>(proj);
    recur7_kernel<<<dim3(256), dim3(320), 0, stream>>>(proj, S0, out);
}

// Round 6
// 470.610 us; speedup vs baseline: 1.1332x; 1.0651x over previous
//
#include <hip/hip_runtime.h>
#include <math.h>
#include <stdint.h>

#define T_DIM 2048
#define B_DIM 16
#define D_DIM 1024
#define N_DIM 64
#define EPSV 1e-6f

#define NT 256   // proj row: 0-63 k, 64-127 v, 128-191 q, 192-255 sigmoid(beta)

#define TWO_LOG2E 2.885390081777927f
#define LOG2E     1.4426950408889634f

typedef _Float16 half8 __attribute__((ext_vector_type(8)));
typedef float    f32x16_t __attribute__((ext_vector_type(16)));
union F4H8 { float4 f; half8 h; };

// ---- fast math ----
__device__ __forceinline__ float fast_rcp(float x) {
    return __builtin_amdgcn_rcpf(x);
}
__device__ __forceinline__ float sigmoid_fast(float x) {
    return fast_rcp(1.f + __builtin_amdgcn_exp2f(-LOG2E * x));
}
// tanh(x) = 1 - 2/(2^(2*log2e*x)+1); caller pre-scales arg by 2*log2e
__device__ __forceinline__ float tanh_from_scaled(float xs) {
    float e = __builtin_amdgcn_exp2f(xs);
    return fmaf(-2.f, fast_rcp(e + 1.f), 1.f);
}

// DPP add: x += dpp_perm(x)
template<int CTRL>
__device__ __forceinline__ float dpp_radd(float x) {
    int y = __builtin_amdgcn_update_dpp(0, __float_as_int(x), CTRL, 0xf, 0xf, true);
    return x + __int_as_float(y);
}
// all-reduce within each 16-lane row (all 16 lanes end with the row sum)
__device__ __forceinline__ float reduce16(float x) {
    x = dpp_radd<0xB1>(x);    // quad_perm [1,0,3,2]
    x = dpp_radd<0x4E>(x);    // quad_perm [2,3,0,1]
    x = dpp_radd<0x124>(x);   // row_ror:4
    x = dpp_radd<0x128>(x);   // row_ror:8
    return x;
}

// async global -> LDS DMA, 16 B per lane; LDS base wave-uniform, lane i -> base + 16*i
__device__ __forceinline__ void dma16(const float* g, float* l) {
    __builtin_amdgcn_global_load_lds((const __attribute__((address_space(1))) void*)g,
                                     (__attribute__((address_space(3))) void*)l, 16, 0, 0);
}

// ======================= W prepass (unchanged) =======================
__global__ __launch_bounds__(256) void wprep_kernel(
    const float* __restrict__ Wk, const float* __restrict__ Wv,
    const float* __restrict__ Wq, const float* __restrict__ Wb,
    float4* __restrict__ w2)
{
    const int c  = threadIdx.x;           // 0..255
    const int k8 = blockIdx.x;            // 0..127
    const float* Wsrc = (c < 64) ? Wk : (c < 128) ? Wv : (c < 192) ? Wq : Wb;
    const float4* src = (const float4*)(Wsrc + (size_t)(c & 63) * D_DIM + k8 * 8);
    const float4 f0 = src[0], f1 = src[1];
    float f[8] = {f0.x, f0.y, f0.z, f0.w, f1.x, f1.y, f1.z, f1.w};
    F4H8 hi, lo;
    #pragma unroll
    for (int j = 0; j < 8; ++j) {
        _Float16 h = (_Float16)f[j];
        hi.h[j] = h;
        lo.h[j] = (_Float16)(f[j] - (float)h);
    }
    w2[(size_t)(2 * k8)     * 256 + c] = hi.f;
    w2[(size_t)(2 * k8 + 1) * 256 + c] = lo.f;
}

// ======================= MFMA projection GEMM (unchanged) =======================
#define BM 64

__global__ __launch_bounds__(256) void proj_gemm_mfma(
    const float* __restrict__ x,
    const float4* __restrict__ w2,
    const float* __restrict__ bb,
    float* __restrict__ proj)
{
    __shared__ float  As32[2][BM * 32];   // fp32 staging, 8 KB each
    __shared__ float4 Ahl[2][BM * 8];     // f16 hi/lo slots, 8 KB each

    const int tid  = threadIdx.x;
    const int w    = tid >> 6;            // wave = col-group wn 0..3
    const int lane = tid & 63;
    const int m0   = blockIdx.x * BM;
    const int cl   = lane & 31;
    const int kh   = lane >> 5;           // k-half of the MFMA operand

    f32x16_t acc[2][2] = {};              // [tm][tn], wave tile 64M x 64N

    auto stage = [&](int buf, int t) {    // fp32 x tile for K-step t
        #pragma unroll
        for (int i = 0; i < 2; ++i) {
            const int rb    = w * 16 + i * 8;
            const int row   = rb + (lane >> 3);
            const int sslot = (lane & 7) ^ ((lane >> 3) & 7);   // pre-swizzled source
            dma16(x + (size_t)(m0 + row) * D_DIM + 32 * t + 4 * sslot,
                  &As32[buf][rb * 32]);
        }
    };
    auto convert = [&](int bs, int bd) {  // fp32 -> f16 hi/lo, once per element
        const int row = tid >> 2, c = tid & 3, sw = row & 7;
        const float4* s32 = (const float4*)&As32[bs][0];
        const float4 fA = s32[row * 8 + ((2 * c)     ^ sw)];
        const float4 fB = s32[row * 8 + ((2 * c + 1) ^ sw)];
        float f[8] = {fA.x, fA.y, fA.z, fA.w, fB.x, fB.y, fB.z, fB.w};
        F4H8 hi, lo;
        #pragma unroll
        for (int j = 0; j < 8; ++j) {
            _Float16 h = (_Float16)f[j];
            hi.h[j] = h;
            lo.h[j] = (_Float16)(f[j] - (float)h);
        }
        Ahl[bd][row * 8 + ((2 * c)     ^ sw)] = hi.f;
        Ahl[bd][row * 8 + ((2 * c + 1) ^ sw)] = lo.f;
    };

    stage(0, 0);
    stage(1, 1);
    __syncthreads();          // both fp32 tiles landed
    convert(0, 0);            // Ahl[0] <- step 0
    __syncthreads();

    for (int t = 0; t < 32; ++t) {
        if (t + 2 < 32) stage(t & 1, t + 2);        // As32[t&1] consumed last iter

        // B fragments for step t straight from L2 (frag-ordered w2)
        half8 bh[2][2], bl[2][2];                   // [ksub][tn]
        #pragma unroll
        for (int ks = 0; ks < 2; ++ks) {
            const int ksg = 2 * t + ks;
            #pragma unroll
            for (int tn = 0; tn < 2; ++tn) {
                const int col = w * 64 + tn * 32 + cl;
                F4H8 th, tl;
                th.f = w2[(size_t)(4 * ksg + 2 * kh)     * 256 + col];
                tl.f = w2[(size_t)(4 * ksg + 2 * kh + 1) * 256 + col];
                bh[ks][tn] = th.h; bl[ks][tn] = tl.h;
            }
        }

        if (t + 1 < 32) convert((t + 1) & 1, (t + 1) & 1);   // hides B-load latency

        const float4* At = &Ahl[t & 1][0];
        #pragma unroll
        for (int ks = 0; ks < 2; ++ks) {
            half8 ah[2], al[2];
            #pragma unroll
            for (int tm = 0; tm < 2; ++tm) {
                const int row = tm * 32 + cl;
                const int sw  = row & 7;
                F4H8 th, tl;
                th.f = At[row * 8 + ((4 * ks + 2 * kh)     ^ sw)];
                tl.f = At[row * 8 + ((4 * ks + 2 * kh + 1) ^ sw)];
                ah[tm] = th.h; al[tm] = tl.h;
            }
            #pragma unroll
            for (int tm = 0; tm < 2; ++tm)
                #pragma unroll
                for (int tn = 0; tn < 2; ++tn) {
                    acc[tm][tn] = __builtin_amdgcn_mfma_f32_32x32x16_f16(ah[tm], bh[ks][tn], acc[tm][tn], 0, 0, 0);
                    acc[tm][tn] = __builtin_amdgcn_mfma_f32_32x32x16_f16(ah[tm], bl[ks][tn], acc[tm][tn], 0, 0, 0);
                    acc[tm][tn] = __builtin_amdgcn_mfma_f32_32x32x16_f16(al[tm], bh[ks][tn], acc[tm][tn], 0, 0, 0);
                }
        }
        __syncthreads();     // drains DMA(t+2); releases As32/Ahl buffers
    }

    // Epilogue: C/D layout col = lane&31, row = (r&3) + 8*(r>>2) + 4*(lane>>5)
    #pragma unroll
    for (int tn = 0; tn < 2; ++tn) {
        const int  gcol   = w * 64 + tn * 32 + cl;
        const bool isbeta = (gcol >= 192);
        const float bias  = isbeta ? bb[gcol - 192] : 0.f;
        #pragma unroll
        for (int tm = 0; tm < 2; ++tm) {
            #pragma unroll
            for (int r = 0; r < 16; ++r) {
                const int rowin = (r & 3) + 8 * (r >> 2) + 4 * kh;
                const size_t grow = (size_t)(m0 + tm * 32 + rowin);
                float v = acc[tm][tn][r];
                if (isbeta) v = sigmoid_fast(v + bias);
                proj[grow * NT + gcol] = v;
            }
        }
    }
}

// ======================= k-normalization (unchanged) =======================
__global__ __launch_bounds__(256) void knorm_kernel(float* __restrict__ proj)
{
    const int w = (int)((blockIdx.x * blockDim.x + threadIdx.x) >> 6);
    const int lane = threadIdx.x & 63;
    float k = proj[(size_t)w * NT + lane];
    float s = k * k;
    #pragma unroll
    for (int off = 32; off; off >>= 1) s += __shfl_xor(s, off, 64);
    proj[(size_t)w * NT + lane] = k * fast_rcp(sqrtf(s) + EPSV);
}

// ======================= recurrence: lean serial wave + offloaded y1 =======================
// 3 waves/block: wv0 = serial (loop-carried chain ONLY), wv1 = y1/output
// (lags one phase, reads s from LDS ring), wv2 = producer (DMA + pre-scale
// v/beta by 2log2e). Serial wave per step: 1 b128 kn read + dot4 + reduce16
// + a = fma(-2L,y2,vC) + 4x(fma,exp2,add,rcp,fma) + 1 b128 ring write.
// Round-3 lesson: straight-line code, no manual interleave.
__device__ __forceinline__ void step_ser(float4& s, const float4 kn,
                                         const float vC, const float beC,
                                         float* __restrict__ ring_dst)
{
    float y2 = (s.x * kn.x + s.y * kn.y) + (s.z * kn.z + s.w * kn.w);
    y2 = reduce16(y2);
    const float a = fmaf(-TWO_LOG2E, y2, vC);       // vC pre-scaled by 2log2e
    const float bsx = beC * s.x, bsy = beC * s.y;   // beC pre-scaled by 2log2e
    const float bsz = beC * s.z, bsw = beC * s.w;
    s.x = tanh_from_scaled(fmaf(a, kn.x, bsx));
    s.y = tanh_from_scaled(fmaf(a, kn.y, bsy));
    s.z = tanh_from_scaled(fmaf(a, kn.z, bsz));
    s.w = tanh_from_scaled(fmaf(a, kn.w, bsw));
    *(float4*)ring_dst = s;                         // for y1 wave (next phase)
}

__device__ __forceinline__ void phase_ser(const float (*buf)[256],
                                          float (*ring)[4][64],
                                          float4& s, int l, int r, int i)
{
    const float* s0 = &buf[0][0];
    const float* s1 = &buf[1][0];
    float4 kn0 = *(const float4*)(s0 + 4 * l);
    float  vC0 = s0[64 + i], beC0 = s0[192 + i];
    float4 kn1 = *(const float4*)(s1 + 4 * l);
    float  vC1 = s1[64 + i], beC1 = s1[192 + i];

    for (int j = 0; j < 8; ++j) {
        const int sp = 2 * j;
        // prefetch next iteration's rows (clamped; row-15 re-read is harmless)
        const int pA = (sp + 2 < 16) ? sp + 2 : 15;
        const int pB = (sp + 3 < 16) ? sp + 3 : 15;
        const float* sA = &buf[pA][0];
        const float* sB = &buf[pB][0];
        float4 knA = *(const float4*)(sA + 4 * l);
        float  vCA = sA[64 + i], beCA = sA[192 + i];
        float4 knB = *(const float4*)(sB + 4 * l);
        float  vCB = sB[64 + i], beCB = sB[192 + i];

        step_ser(s, kn0, vC0, beC0, &ring[sp][r][4 * l]);
        step_ser(s, kn1, vC1, beC1, &ring[sp + 1][r][4 * l]);

        kn0 = knA; vC0 = vCA; beC0 = beCA;
        kn1 = knB; vC1 = vCB; beC1 = beCB;
    }
}

__device__ __forceinline__ void phase_y1(const float (*ring)[4][64],
                                         const float* __restrict__ proj,
                                         int t0, int b, int l, int r, int i,
                                         float* __restrict__ out)
{
    // q for the 16 steps, straight from global (L2-hot: producer DMA'd it)
    float4 q[16];
    #pragma unroll
    for (int sp = 0; sp < 16; ++sp)
        q[sp] = *(const float4*)(proj + ((size_t)(t0 + sp) * B_DIM + b) * NT + 128 + 4 * l);
    float ysel = 0.f;
    #pragma unroll
    for (int sp = 0; sp < 16; ++sp) {
        const float4 sv = *(const float4*)(&ring[sp][r][4 * l]);
        float y1 = (sv.x * q[sp].x + sv.y * q[sp].y) + (sv.z * q[sp].z + sv.w * q[sp].w);
        y1 = reduce16(y1);
        ysel = (l == sp) ? y1 : ysel;       // lane l keeps step t0+l of row i
    }
    const float w = ysel;
    out[(size_t)(t0 + l) * (B_DIM * N_DIM) + b * 64 + i] = w * w * sigmoid_fast(w);
}

__global__ __launch_bounds__(192, 1) void recur8_kernel(
    const float* __restrict__ proj,
    const float* __restrict__ S0,
    float* __restrict__ out)   // [T,B,N] then S_final [B,N,N]
{
    __shared__ float buf[2][16][256];     // staged proj rows (v/beta pre-scaled)
    __shared__ float ring[2][16][4][64];  // post-update s per step, dbuf by phase

    const int wid  = blockIdx.x;          // [0,256)
    const int wv   = threadIdx.x >> 6;    // 0 serial, 1 y1, 2 producer
    const int lane = threadIdx.x & 63;
    const int l = lane & 15;
    const int r = lane >> 4;
    const int b = wid >> 4;
    const int i = ((wid & 15) << 2) + r;

    if (wv == 2) {
        // ---- producer: DMA 16 rows + pre-scale v/beta sections ----
        auto fill = [&](int pb, int tfirst) {
            #pragma unroll
            for (int j = 0; j < 16; ++j) {
                int row = tfirst + j; if (row > T_DIM - 1) row = T_DIM - 1;
                dma16(proj + ((size_t)row * B_DIM + b) * NT + 4 * lane, &buf[pb][j][0]);
            }
            asm volatile("s_waitcnt vmcnt(0)");
            #pragma unroll
            for (int j = 0; j < 16; ++j) {
                buf[pb][j][64 + lane]  *= TWO_LOG2E;
                buf[pb][j][192 + lane] *= TWO_LOG2E;
            }
        };
        fill(0, 0);
        __syncthreads();                  // prologue: buf[0] ready
        for (int p = 0; p < 128; ++p) {
            fill((p + 1) & 1, 16 * (p + 1));   // p=127 refills clamped junk (harmless)
            __syncthreads();
        }
    } else if (wv == 0) {
        // ---- serial wave: the 2048-step loop-carried chain ----
        __builtin_amdgcn_s_setprio(1);
        float4 s = *(const float4*)(S0 + ((size_t)(b * 64 + i) << 6) + 4 * l);
        __syncthreads();
        for (int p = 0; p < 128; ++p) {
            phase_ser(buf[p & 1], ring[p & 1], s, l, r, i);
            __syncthreads();
        }
        *(float4*)(out + (size_t)T_DIM * B_DIM * N_DIM +
                   ((size_t)(b * 64 + i) << 6) + 4 * l) = s;
    } else {
        // ---- y1 wave: lags one phase behind the serial wave ----
        __syncthreads();
        for (int p = 0; p < 128; ++p) {
            if (p >= 1)
                phase_y1(ring[(p - 1) & 1], proj, 16 * (p - 1), b, l, r, i, out);
            __syncthreads();
        }
        phase_y1(ring[1], proj, 16 * 127, b, l, r, i, out);   // final phase
    }
}

extern "C" void kernel_launch(void* const* d_in, const int* in_sizes, int n_in,
                              void* d_out, int out_size, void* d_ws, size_t ws_size,
                              hipStream_t stream) {
    const float* x  = (const float*)d_in[0];
    const float* S0 = (const float*)d_in[1];
    const float* Wk = (const float*)d_in[2];
    const float* Wv = (const float*)d_in[3];
    const float* Wq = (const float*)d_in[4];
    const float* Wb = (const float*)d_in[5];
    const float* bb = (const float*)d_in[6];
    float* out  = (float*)d_out;
    float* proj = (float*)d_ws;                       // 32768*256 f32 = 32 MB
    float4* w2  = (float4*)((char*)d_ws + (size_t)32768 * 256 * 4);   // +1 MB

    wprep_kernel<<<dim3(128), dim3(256), 0, stream>>>(Wk, Wv, Wq, Wb, w2);
    proj_gemm_mfma<<<dim3(32768 / BM), dim3(256), 0, stream>>>(x, w2, bb, proj);
    knorm_kernel<<<dim3((32768 * 64) / 256), dim3(256), 0, stream>>>(proj);
    recur8_kernel<<<dim3(256), dim3(192), 0, stream>>>(proj, S0, out);
}